// Round 1
// 447.700 us; speedup vs baseline: 1.0261x; 1.0261x over previous
//
#include <hip/hip_runtime.h>

// Problem constants (reference: B=64, L=1024, D=1280)
#define BB 64
#define LL 1024
#define DD 1280
#define SPLITS 32       // token splits for the pool
#define CHUNK 32        // L / SPLITS
#define CC 20           // column chunks of 64 (20*64 = 1280)
#define BG 16           // b-groups of 4 (16*4 = 64)
#define WD 320          // d-range per wave in gemm (DD / 4 waves)

// ---------------------------------------------------------------------------
// Kernel 1: ragged partial sum pool, pre-scaled by 1/pool_len (distributive:
// sum_s(partial_s)/n == sum_s(partial_s/n)), so kernel 2 is a pure sum.
// grid = (SPLITS, B) = 2048 blocks, block = 320 threads (5 waves) -> 6
// blocks/CU = 30 waves/CU for HBM latency hiding. Thread t owns float4 #t of
// each 1280-float row; one block iteration reads one full row (5120 B),
// coalesced 16 B/lane. Inactive splits write zeros (no ws pre-zero needed).
// unroll 8: 8 outstanding 16B loads/lane -> ~45 B/cyc/CU in flight vs the
// ~10.3 B/cyc/CU needed to saturate 6.3 TB/s.
// ---------------------------------------------------------------------------
__global__ __launch_bounds__(320) void pool_partial(
    const float* __restrict__ prev, const int* __restrict__ lengths,
    float* __restrict__ P) {
  const int s = blockIdx.x;
  const int b = blockIdx.y;
  const int t = threadIdx.x;  // [0, 320)

  const int pool_len = lengths[b] + 2;  // in [2, 1023]
  const float inv = 1.0f / (float)pool_len;
  const int l0 = s * CHUNK;
  const int l1 = min(pool_len, l0 + CHUNK);

  float4 acc = make_float4(0.f, 0.f, 0.f, 0.f);
  const float* base = prev + (size_t)b * LL * DD + 4 * t;
#pragma unroll 8
  for (int l = l0; l < l1; ++l) {
    const float4 v = *(const float4*)(base + (size_t)l * DD);
    acc.x += v.x; acc.y += v.y; acc.z += v.z; acc.w += v.w;
  }
  acc.x *= inv; acc.y *= inv; acc.z *= inv; acc.w *= inv;
  float4* dst = (float4*)(P + ((size_t)s * BB + b) * DD) + t;
  *dst = acc;  // unconditional: inactive splits write zeros
}

// ---------------------------------------------------------------------------
// Kernel 2: emb[b][d] = sum_s P[s][b][d] (already scaled). Also initializes
// out[b] = cls_b (kernel 3 accumulates into it with atomics).
// grid = B, block = 320 (thread t owns float4 #t of emb[b]).
// ---------------------------------------------------------------------------
__global__ __launch_bounds__(320) void emb_reduce(
    const float* __restrict__ P, const float* __restrict__ cls_b,
    float* __restrict__ emb, float* __restrict__ out) {
  const int b = blockIdx.x;
  const int t = threadIdx.x;

  float4 acc = make_float4(0.f, 0.f, 0.f, 0.f);
#pragma unroll
  for (int s = 0; s < SPLITS; ++s) {
    const float4 v = *((const float4*)(P + ((size_t)s * BB + b) * DD) + t);
    acc.x += v.x; acc.y += v.y; acc.z += v.z; acc.w += v.w;
  }
  *((float4*)(emb + (size_t)b * DD) + t) = acc;
  if (t == 0) out[b] = cls_b[0];
}

// ---------------------------------------------------------------------------
// Kernel 3: per (b, col): relu(emb[b]·W[:,col] + bias[col]) * cls_w[col],
// reduced over cols into out[b] via one atomicAdd per wave.
// grid = (CC, BG) = 320 blocks, block = 256 = 4 waves.
//
// d-SPLIT ACROSS WAVES (new): wave w covers d in [320w, 320w+320) for ALL 4
// b's of the group, instead of 4 waves redundantly streaming the same W
// slice. W/L1 traffic per block: 1.31 MB -> 327 KB (4x). LDS reads per
// block: 5120 ds_read_b32 -> 1280 ds_read_b128 broadcasts (4x fewer instrs,
// each feeding 4 FMAs). emb staged TRANSPOSED: es4[d] = {e[b0][d]..e[b3][d]}
// so one broadcast b128 read serves all 4 accumulators. Cross-wave combine
// through a 4 KB LDS partial buffer (lane-indexed, conflict-free), then
// bias+relu+cls_w, wave shuffle-reduce, one atomicAdd per (block, b).
// ---------------------------------------------------------------------------
__global__ __launch_bounds__(256) void gemm_relu_out(
    const float* __restrict__ emb, const float* __restrict__ W,
    const float* __restrict__ bias, const float* __restrict__ cls_w,
    float* __restrict__ out) {
  __shared__ float4 es4[DD];        // es4[d] = {emb[b0][d],...,emb[b3][d]}
  __shared__ float part[4][4][64];  // [producer wave][b-idx][lane]

  const int cc = blockIdx.x;
  const int bg = blockIdx.y;
  const int t = threadIdx.x;
  const int lane = t & 63;
  const int wave = t >> 6;          // 0..3 -> which d-range
  const int col = cc * 64 + lane;

  // Transpose-stage 4 emb rows: coalesced global reads, scattered LDS writes
  // (80 wave-instrs total; bank cost negligible).
  const float* eg = emb + (size_t)bg * 4 * DD;
  float* est = (float*)es4;
#pragma unroll
  for (int k = 0; k < 20; ++k) {
    const int i = k * 256 + t;      // i = j*1280 + d, i < 5120
    const int j = i / DD;           // b-idx 0..3
    const int d = i - j * DD;
    est[d * 4 + j] = eg[i];
  }
  __syncthreads();

  // Each wave: 320 d-iterations, 1 coalesced W load + 1 broadcast b128 LDS
  // read + 4 FMAs per iteration.
  const float* wp = W + (size_t)wave * WD * DD + col;
  float a0 = 0.f, a1 = 0.f, a2 = 0.f, a3 = 0.f;
#pragma unroll 8
  for (int d = 0; d < WD; ++d) {
    const float wv = wp[(size_t)d * DD];
    const float4 e = es4[wave * WD + d];
    a0 = fmaf(e.x, wv, a0);
    a1 = fmaf(e.y, wv, a1);
    a2 = fmaf(e.z, wv, a2);
    a3 = fmaf(e.w, wv, a3);
  }
  part[wave][0][lane] = a0;
  part[wave][1][lane] = a1;
  part[wave][2][lane] = a2;
  part[wave][3][lane] = a3;
  __syncthreads();

  // Wave w finalizes b = bg*4 + w: sum the 4 d-range partials for its b.
  float v = part[0][wave][lane] + part[1][wave][lane] +
            part[2][wave][lane] + part[3][wave][lane] + bias[col];
  v = fmaxf(v, 0.f) * cls_w[col];

  // Wave-level reduction over the 64 cols.
#pragma unroll
  for (int off = 32; off > 0; off >>= 1) v += __shfl_down(v, off);
  if (lane == 0) atomicAdd(out + bg * 4 + wave, v);
}

extern "C" void kernel_launch(void* const* d_in, const int* in_sizes, int n_in,
                              void* d_out, int out_size, void* d_ws, size_t ws_size,
                              hipStream_t stream) {
  const float* prev    = (const float*)d_in[0];  // [B, L, D] f32
  const int*   lengths = (const int*)d_in[1];    // [B] i32
  const float* dense_w = (const float*)d_in[2];  // [D, D] f32
  const float* dense_b = (const float*)d_in[3];  // [D] f32
  const float* cls_w   = (const float*)d_in[4];  // [D, 1] f32
  const float* cls_b   = (const float*)d_in[5];  // [1] f32
  float* out = (float*)d_out;                    // [B] f32

  // Workspace: P [SPLITS*B*D] floats (10.5 MB), emb [B*D] floats (327 KB).
  float* P = (float*)d_ws;
  float* emb = P + (size_t)SPLITS * BB * DD;

  pool_partial<<<dim3(SPLITS, BB), 320, 0, stream>>>(prev, lengths, P);
  emb_reduce<<<BB, 320, 0, stream>>>(P, cls_b, emb, out);
  gemm_relu_out<<<dim3(CC, BG), 256, 0, stream>>>(emb, dense_w, dense_b,
                                                  cls_w, out);
}